// Round 8
// baseline (577.149 us; speedup 1.0000x reference)
//
#include <hip/hip_runtime.h>

#define NT   512
#define IMPN (2048 * 512)
#define HROW 72                      // ushorts per h_lds seq-row (144 B)

typedef __attribute__((ext_vector_type(8))) short short8v;
typedef __attribute__((ext_vector_type(4))) float f32x4;

union Frag { short8v v; unsigned short s[8]; };

__device__ __forceinline__ float fsig(float x) {
    return __builtin_amdgcn_rcpf(1.0f + __expf(-x));
}
__device__ __forceinline__ float ftanh(float x) {
    return 2.0f * __builtin_amdgcn_rcpf(1.0f + __expf(-2.0f * x)) - 1.0f;
}
__device__ __forceinline__ unsigned short f2bf(float f) {
    unsigned u = __float_as_uint(f);
    unsigned r = u + 0x7FFFu + ((u >> 16) & 1u);
    return (unsigned short)(r >> 16);
}
__device__ __forceinline__ float bf2f(unsigned short s) {
    return __uint_as_float(((unsigned)s) << 16);
}
__device__ __forceinline__ unsigned cvt_pk_bf16(float a, float b) {
    unsigned r;
    asm("v_cvt_pk_bf16_f32 %0, %1, %2" : "=v"(r) : "v"(a), "v"(b));
    return r;
}

// 128 blocks x 512 threads, 1 block/CU, 2 waves/SIMD. Each block = TWO
// independent 16-seq groups (waves 0-3 / 4-7): chip has exactly 1024 useful
// waves (4096 seq-dirs / 4 seqs-per-wave), so 2 groups/CU on 128 CUs trades
// idle CUs for 2 instruction streams per SIMD -> group A's MFMA exec overlaps
// group B's gate VALU/trans (R7 showed 1-wave/SIMD serializes the two pipes).
// Within a group: TRANSPOSED MFMA (weights = A operand, h = B operand),
// D[gate-row][seq]: lane (j,g) owns seq j, units 16w+4g+{0..3}. acc3 = xh via
// rW-broadcast rows. 3-product bf16 split {HH, HL, LH}: per-product err
// ~3*2^-16, contractive GRU -> final err few e-4 (output bf16 floor 2^-9).
// dir=1 consumes time REVERSED; imp stored at scan index.
__global__ __launch_bounds__(512, 1) void brits_mfma(
    const float* __restrict__ input,
    const float* __restrict__ gW_f, const float* __restrict__ gb_f,
    const float* __restrict__ rW_f, const float* __restrict__ rb_f,
    const float* __restrict__ fcW_f, const float* __restrict__ fcb_f,
    const float* __restrict__ Wih_f, const float* __restrict__ bih_f,
    const float* __restrict__ Whh_f, const float* __restrict__ bhh_f,
    const float* __restrict__ gW_b, const float* __restrict__ gb_b,
    const float* __restrict__ rW_b, const float* __restrict__ rb_b,
    const float* __restrict__ fcW_b, const float* __restrict__ fcb_b,
    const float* __restrict__ Wih_b, const float* __restrict__ bih_b,
    const float* __restrict__ Whh_b, const float* __restrict__ bhh_b,
    float* __restrict__ out, float* __restrict__ ws)
{
    __shared__ __align__(16) unsigned short h_lds[2][2][2][16 * HROW]; // [grp][buf][lev]
    __shared__ __align__(16) float xmd_l[2][16][17][4];                // [grp][seq][tau][x,m,d,-]
    __shared__ __align__(16) float impbuf[2][16][17];
    __shared__ __align__(16) float fcpart[2][16][4];

    const int tid  = threadIdx.x;
    const int w8   = tid >> 6;           // 0..7
    const int grp  = w8 >> 2;            // 0,1: independent seq-group
    const int w    = w8 & 3;             // wave within group
    const int lane = tid & 63;
    const int j    = lane & 15;          // seq owned by this lane
    const int g    = lane >> 4;
    const int u    = w * 16 + j;         // weight-frag row unit
    const int u0   = w * 16 + 4 * g;     // first of this lane's 4 gate units
    const int gid  = blockIdx.x * 2 + grp;   // 0..255
    const int dir  = gid >> 7;
    const int b0   = (gid & 127) * 16;

    const float* gW  = dir ? gW_b  : gW_f;
    const float* gb  = dir ? gb_b  : gb_f;
    const float* rW  = dir ? rW_b  : rW_f;
    const float* rb  = dir ? rb_b  : rb_f;
    const float* fcW = dir ? fcW_b : fcW_f;
    const float* Wih = dir ? Wih_b : Wih_f;
    const float* bih = dir ? bih_b : bih_f;
    const float* Whh = dir ? Whh_b : Whh_f;
    const float* bhh = dir ? bhh_b : bhh_f;

    // per-lane per-q constants (units u0..u0+3)
    float gWq[4], gbq[4], fcq[4], wxr[4], wmr[4], wxz[4], wmz[4], wxn[4], wmn[4];
    float brq[4], bzq[4], binq[4], bhnq[4];
#pragma unroll
    for (int q = 0; q < 4; ++q) {
        const int uq = u0 + q;
        gWq[q] = gW[uq]; gbq[q] = gb[uq]; fcq[q] = fcW[uq];
        wxr[q] = Wih[2 * uq];         wmr[q] = Wih[2 * uq + 1];
        wxz[q] = Wih[2 * (64 + uq)];  wmz[q] = Wih[2 * (64 + uq) + 1];
        wxn[q] = Wih[2 * (128 + uq)]; wmn[q] = Wih[2 * (128 + uq) + 1];
        brq[q] = bih[uq] + bhh[uq];
        bzq[q] = bih[64 + uq] + bhh[64 + uq];
        binq[q] = bih[128 + uq]; bhnq[q] = bhh[128 + uq];
    }
    const float rb0 = rb[0];

    // weight A-fragments: 4 targets (r,z,n,xh) x 2 k-tiles x 2 levels.
    Frag Wf[4][2][2];
#pragma unroll
    for (int t = 0; t < 4; ++t) {
        const float* src = (t < 3) ? (Whh + (t * 64 + u) * 64) : rW;
#pragma unroll
        for (int kt = 0; kt < 2; ++kt) {
#pragma unroll
            for (int e = 0; e < 8; ++e) {
                const float v = src[kt * 32 + g * 8 + e];
                const unsigned short bH = f2bf(v);
                const unsigned short bL = f2bf(v - bf2f(bH));  // RNE residual
                Wf[t][kt][0].s[e] = bH;
                Wf[t][kt][1].s[e] = bL;
            }
        }
    }

    float h[4] = {0.0f, 0.0f, 0.0f, 0.0f};   // units u0..u0+3, seq j

    for (int t = 0; t < NT; ++t) {
        const int tm = t & 15;
        if (tm == 0) {                            // 16-step chunk boundary
            __syncthreads();
            // staging threads cover BOTH groups: (grp_s, s, tau)
            const int grp_s = tid >> 8, s = (tid >> 4) & 15, tmi = tid & 15;
            const int gid_s = blockIdx.x * 2 + grp_s;
            const int dir_s = gid_s >> 7;
            const int b0_s  = (gid_s & 127) * 16;
            if (t > 0) {                          // coalesced imp flush
                out[2048 + (size_t)dir_s * IMPN + (size_t)(b0_s + s) * NT + (t - 16) + tmi]
                    = impbuf[grp_s][s][tmi];
            }
            {                                     // stage x/m/d chunk (scan order)
                const float* base = input + (size_t)(b0_s + s) * 3072;
                const int tt = dir_s ? (NT - 1 - t - tmi) : (t + tmi);
                float x = base[tt];
                x = (x != x) ? -1.0f : x;
                const float m  = base[2 * NT + tt];
                const float dd = base[3 * NT + tt];
                float4 v; v.x = x; v.y = m; v.z = dd; v.w = 0.0f;
                *(float4*)&xmd_l[grp_s][s][tmi][0] = v;
            }
            __syncthreads();
        }
        const int buf = t & 1;

        // ---- phase A: seq-j scalars, decay, pack H/L, publish (2x b64) ----
        const float4 xmd = *(const float4*)&xmd_l[grp][j][tm][0];   // x, m, d
#pragma unroll
        for (int q = 0; q < 4; ++q) h[q] *= fsig(xmd.z * gWq[q] + gbq[q]);

        const unsigned pH0 = cvt_pk_bf16(h[0], h[1]);
        const unsigned pH1 = cvt_pk_bf16(h[2], h[3]);
        const float l0 = h[0] - __uint_as_float(pH0 << 16);
        const float l1 = h[1] - __uint_as_float(pH0 & 0xFFFF0000u);
        const float l2 = h[2] - __uint_as_float(pH1 << 16);
        const float l3 = h[3] - __uint_as_float(pH1 & 0xFFFF0000u);
        const unsigned pL0 = cvt_pk_bf16(l0, l1);
        const unsigned pL1 = cvt_pk_bf16(l2, l3);
        {
            const int off = j * HROW + u0;        // ushort index, 8B-aligned
            uint2 vH; vH.x = pH0; vH.y = pH1;
            uint2 vL; vL.x = pL0; vL.y = pL1;
            *(uint2*)&h_lds[grp][buf][0][off] = vH;
            *(uint2*)&h_lds[grp][buf][1][off] = vL;
        }
        __syncthreads();

        // ---- phase B: h B-frags (4x ds_read_b128) + 24 MFMA (xh first, z last) ----
        Frag A[2][2];
#pragma unroll
        for (int kt = 0; kt < 2; ++kt)
#pragma unroll
            for (int lev = 0; lev < 2; ++lev)
                A[kt][lev].v = *(const short8v*)&h_lds[grp][buf][lev][j * HROW + kt * 32 + 8 * g];

        f32x4 acc0 = {0,0,0,0}, acc1 = {0,0,0,0}, acc2 = {0,0,0,0}, acc3 = {0,0,0,0};
#pragma unroll
        for (int kt = 0; kt < 2; ++kt) {
            acc3 = __builtin_amdgcn_mfma_f32_16x16x32_bf16(Wf[3][kt][0].v, A[kt][0].v, acc3, 0, 0, 0);
            acc0 = __builtin_amdgcn_mfma_f32_16x16x32_bf16(Wf[0][kt][0].v, A[kt][0].v, acc0, 0, 0, 0);
            acc2 = __builtin_amdgcn_mfma_f32_16x16x32_bf16(Wf[2][kt][0].v, A[kt][0].v, acc2, 0, 0, 0);
            acc1 = __builtin_amdgcn_mfma_f32_16x16x32_bf16(Wf[1][kt][0].v, A[kt][0].v, acc1, 0, 0, 0);
            acc3 = __builtin_amdgcn_mfma_f32_16x16x32_bf16(Wf[3][kt][0].v, A[kt][1].v, acc3, 0, 0, 0);
            acc0 = __builtin_amdgcn_mfma_f32_16x16x32_bf16(Wf[0][kt][0].v, A[kt][1].v, acc0, 0, 0, 0);
            acc2 = __builtin_amdgcn_mfma_f32_16x16x32_bf16(Wf[2][kt][0].v, A[kt][1].v, acc2, 0, 0, 0);
            acc1 = __builtin_amdgcn_mfma_f32_16x16x32_bf16(Wf[1][kt][0].v, A[kt][1].v, acc1, 0, 0, 0);
            acc3 = __builtin_amdgcn_mfma_f32_16x16x32_bf16(Wf[3][kt][1].v, A[kt][0].v, acc3, 0, 0, 0);
            acc0 = __builtin_amdgcn_mfma_f32_16x16x32_bf16(Wf[0][kt][1].v, A[kt][0].v, acc0, 0, 0, 0);
            acc2 = __builtin_amdgcn_mfma_f32_16x16x32_bf16(Wf[2][kt][1].v, A[kt][0].v, acc2, 0, 0, 0);
            acc1 = __builtin_amdgcn_mfma_f32_16x16x32_bf16(Wf[1][kt][1].v, A[kt][0].v, acc1, 0, 0, 0);
        }

        // ---- phase C: per-seq scalars once, then 4 units of gates ----
        const float xh = acc3[0] + rb0;           // all acc3 rows identical (bcast A)
        if (w == 0 && g == 0) impbuf[grp][j][tm] = xh;
        const float mv = xmd.y;
        const float xc = mv * xmd.x + (1.0f - mv) * xh;
#pragma unroll
        for (int q = 0; q < 4; ++q) {
            const float an = wxn[q] * xc + wmn[q] * mv + binq[q];   // indep of rr
            const float bn = acc2[q] + bhnq[q];                     // indep of rr
            const float rr = fsig(acc0[q] + wxr[q] * xc + wmr[q] * mv + brq[q]);
            const float zz = fsig(acc1[q] + wxz[q] * xc + wmz[q] * mv + bzq[q]);
            const float nn = ftanh(an + rr * bn);
            h[q] = nn + zz * (h[q] - nn);
        }
    }

    // epilogue: flush last imp chunk + fc reduction
    __syncthreads();
    {
        const int grp_s = tid >> 8, s = (tid >> 4) & 15, tmi = tid & 15;
        const int gid_s = blockIdx.x * 2 + grp_s;
        const int dir_s = gid_s >> 7;
        const int b0_s  = (gid_s & 127) * 16;
        out[2048 + (size_t)dir_s * IMPN + (size_t)(b0_s + s) * NT + (NT - 16) + tmi]
            = impbuf[grp_s][s][tmi];
    }
    float pfc = h[0] * fcq[0] + h[1] * fcq[1] + h[2] * fcq[2] + h[3] * fcq[3];
    pfc += __shfl_xor(pfc, 16);
    pfc += __shfl_xor(pfc, 32);
    if (lane < 16) fcpart[grp][j][w] = pfc;
    __syncthreads();
    if (tid < 32) {
        const int g2 = tid >> 4, jj = tid & 15;
        const int gid2 = blockIdx.x * 2 + g2;
        const int dir2 = gid2 >> 7;
        const int b02  = (gid2 & 127) * 16;
        const float* fcb = dir2 ? fcb_b : fcb_f;
        float4 xp = *(const float4*)&fcpart[g2][jj][0];
        ws[dir2 * 2048 + b02 + jj] = xp.x + xp.y + xp.z + xp.w + fcb[0];
    }
}

__global__ void brits_combine(const float* __restrict__ ws, float* __restrict__ out)
{
    int i = blockIdx.x * 256 + threadIdx.x;
    if (i < 2048) out[i] = 0.5f * (ws[i] + ws[2048 + i]);
}

extern "C" void kernel_launch(void* const* d_in, const int* in_sizes, int n_in,
                              void* d_out, int out_size, void* d_ws, size_t ws_size,
                              hipStream_t stream)
{
    const float* p[21];
    for (int i = 0; i < 21; ++i) p[i] = (const float*)d_in[i];
    float* out = (float*)d_out;
    float* ws  = (float*)d_ws;   // 4096 floats used

    brits_mfma<<<128, 512, 0, stream>>>(
        p[0],
        p[1], p[2], p[3], p[4], p[5], p[6], p[7], p[8], p[9], p[10],
        p[11], p[12], p[13], p[14], p[15], p[16], p[17], p[18], p[19], p[20],
        out, ws);
    brits_combine<<<8, 256, 0, stream>>>(ws, out);
}

// Round 9
// 470.783 us; speedup vs baseline: 1.2259x; 1.2259x over previous
//
#include <hip/hip_runtime.h>

#define NT   512
#define IMPN (2048 * 512)
#define HROW 72                      // ushorts per h_lds seq-row (144 B, 16B-aligned)

typedef __attribute__((ext_vector_type(8))) short short8v;
typedef __attribute__((ext_vector_type(4))) float f32x4;

union Frag { short8v v; unsigned short s[8]; };

#define L2E 1.4426950408889634f

// sigmoid in exp2-prescaled space: arg y2 = y_natural * log2(e)
__device__ __forceinline__ float fsig2(float y2) {
    return __builtin_amdgcn_rcpf(1.0f + exp2f(-y2));
}
__device__ __forceinline__ unsigned short f2bf(float f) {
    unsigned u = __float_as_uint(f);
    unsigned r = u + 0x7FFFu + ((u >> 16) & 1u);
    return (unsigned short)(r >> 16);
}
__device__ __forceinline__ float bf2f(unsigned short s) {
    return __uint_as_float(((unsigned)s) << 16);
}
__device__ __forceinline__ unsigned cvt_pk_bf16(float a, float b) {
    unsigned r;
    asm("v_cvt_pk_bf16_f32 %0, %1, %2" : "=v"(r) : "v"(a), "v"(b));
    return r;
}

// 256 blocks x 256 threads, 1 block/CU (1024 full-lane waves = 1/SIMD chip-wide;
// R6/R8 showed any 2-stream variant wastes lanes or idles CUs). Blocks 0..127
// fwd, 128..255 bwd; block = 16 seqs. TRANSPOSED MFMA (weights = A, h = B):
// D[gate-row][seq], lane (j,g) owns seq j, units 16w+4g+{0..3}.
// 18 MFMA/step: r,z,n targets x 2 kt x 3-product bf16 split {HH, HL, LH}
// (per-product err ~3*2^-16; contractive GRU -> final err few e-4).
// xh = rW.h done OUTSIDE MFMA: per-wave 4-lane shuffle partial + xhp LDS
// exchange (fp32-exact, frees 6 MFMA).
// exp2 PRESCALING: Whh r/z rows, wxr/wmr/br, wxz/wmz/bz, gW/gb scaled by
// log2e; n-path (Whh n rows, wxn/wmn/bin/bhn) scaled by 2*log2e ->
// sigmoid(y)=rcp(1+exp2(-y2)), tanh(x)=2*rcp(1+exp2(-x2))-1, no mul in chain.
// dir=1 consumes time REVERSED; imp stored at scan index.
__global__ __launch_bounds__(256, 1) void brits_mfma(
    const float* __restrict__ input,
    const float* __restrict__ gW_f, const float* __restrict__ gb_f,
    const float* __restrict__ rW_f, const float* __restrict__ rb_f,
    const float* __restrict__ fcW_f, const float* __restrict__ fcb_f,
    const float* __restrict__ Wih_f, const float* __restrict__ bih_f,
    const float* __restrict__ Whh_f, const float* __restrict__ bhh_f,
    const float* __restrict__ gW_b, const float* __restrict__ gb_b,
    const float* __restrict__ rW_b, const float* __restrict__ rb_b,
    const float* __restrict__ fcW_b, const float* __restrict__ fcb_b,
    const float* __restrict__ Wih_b, const float* __restrict__ bih_b,
    const float* __restrict__ Whh_b, const float* __restrict__ bhh_b,
    float* __restrict__ out, float* __restrict__ ws)
{
    __shared__ __align__(16) unsigned short h_lds[2][2][16 * HROW]; // [buf][lev][seq*HROW+unit]
    __shared__ __align__(16) float xhp[2][16][4];                   // [buf][seq][wave] xh partials
    __shared__ __align__(16) float xmd_l[16][17][4];                // [seq][tau(+pad)][x,m,d,-]
    __shared__ __align__(16) float impbuf[16][17];
    __shared__ __align__(16) float fcpart[16][4];

    const int tid  = threadIdx.x;
    const int w    = tid >> 6;
    const int lane = tid & 63;
    const int j    = lane & 15;          // seq owned by this lane
    const int g    = lane >> 4;
    const int u    = w * 16 + j;         // weight-frag row unit
    const int u0   = w * 16 + 4 * g;     // first of this lane's 4 gate units
    const int dir  = blockIdx.x >> 7;
    const int b0   = (blockIdx.x & 127) * 16;

    const float* gW  = dir ? gW_b  : gW_f;
    const float* gb  = dir ? gb_b  : gb_f;
    const float* rW  = dir ? rW_b  : rW_f;
    const float* rb  = dir ? rb_b  : rb_f;
    const float* fcW = dir ? fcW_b : fcW_f;
    const float* fcb = dir ? fcb_b : fcb_f;
    const float* Wih = dir ? Wih_b : Wih_f;
    const float* bih = dir ? bih_b : bih_f;
    const float* Whh = dir ? Whh_b : Whh_f;
    const float* bhh = dir ? bhh_b : bhh_f;

    // per-lane per-q constants (units u0..u0+3), exp2-prescaled
    float gW2[4], gb2[4], fcq[4], rWq[4];
    float wxr[4], wmr[4], wxz[4], wmz[4], wxn[4], wmn[4];
    float brq[4], bzq[4], binq[4], bhnq[4];
#pragma unroll
    for (int q = 0; q < 4; ++q) {
        const int uq = u0 + q;
        gW2[q] = gW[uq] * L2E; gb2[q] = gb[uq] * L2E;
        fcq[q] = fcW[uq]; rWq[q] = rW[uq];
        wxr[q] = Wih[2 * uq] * L2E;                wmr[q] = Wih[2 * uq + 1] * L2E;
        wxz[q] = Wih[2 * (64 + uq)] * L2E;         wmz[q] = Wih[2 * (64 + uq) + 1] * L2E;
        wxn[q] = Wih[2 * (128 + uq)] * 2.0f * L2E; wmn[q] = Wih[2 * (128 + uq) + 1] * 2.0f * L2E;
        brq[q]  = (bih[uq] + bhh[uq]) * L2E;
        bzq[q]  = (bih[64 + uq] + bhh[64 + uq]) * L2E;
        binq[q] = bih[128 + uq] * 2.0f * L2E;
        bhnq[q] = bhh[128 + uq] * 2.0f * L2E;
    }
    const float rb0 = rb[0];

    // weight A-fragments: 3 targets (r,z,n) x 2 k-tiles x 2 levels, prescaled.
    Frag Wf[3][2][2];
#pragma unroll
    for (int t = 0; t < 3; ++t) {
        const float* src = Whh + (t * 64 + u) * 64;
        const float sc = (t == 2) ? (2.0f * L2E) : L2E;
#pragma unroll
        for (int kt = 0; kt < 2; ++kt) {
#pragma unroll
            for (int e = 0; e < 8; ++e) {
                const float v = src[kt * 32 + g * 8 + e] * sc;
                const unsigned short bH = f2bf(v);
                const unsigned short bL = f2bf(v - bf2f(bH));  // RNE residual
                Wf[t][kt][0].s[e] = bH;
                Wf[t][kt][1].s[e] = bL;
            }
        }
    }

    const float* inp = input + (size_t)b0 * 3072;
    float* impOut = out + 2048 + (size_t)dir * IMPN + (size_t)b0 * NT;

    float h[4] = {0.0f, 0.0f, 0.0f, 0.0f};   // units u0..u0+3, seq j

    for (int t = 0; t < NT; ++t) {
        const int tm = t & 15;
        if (tm == 0) {                            // 16-step chunk boundary
            __syncthreads();
            const int s = tid >> 4, tmi = tid & 15;
            if (t > 0) {                          // coalesced imp flush
                impOut[s * NT + (t - 16) + tmi] = impbuf[s][tmi];
            }
            {                                     // stage x/m/d chunk (scan order)
                const float* base = inp + (size_t)s * 3072;
                const int tt = dir ? (NT - 1 - t - tmi) : (t + tmi);
                float x = base[tt];
                x = (x != x) ? -1.0f : x;
                const float m  = base[2 * NT + tt];
                const float dd = base[3 * NT + tt];
                float4 v; v.x = x; v.y = m; v.z = dd; v.w = 0.0f;
                *(float4*)&xmd_l[s][tmi][0] = v;
            }
            __syncthreads();
        }
        const int buf = t & 1;

        // ---- phase A: decay, xh partial (shuffle), pack H/L, publish ----
        const float4 xmd = *(const float4*)&xmd_l[j][tm][0];   // x, m, d
#pragma unroll
        for (int q = 0; q < 4; ++q) h[q] *= fsig2(xmd.z * gW2[q] + gb2[q]);

        // xh partial over this wave's 16 units (fp32-exact)
        float p = h[0] * rWq[0] + h[1] * rWq[1] + h[2] * rWq[2] + h[3] * rWq[3];
        p += __shfl_xor(p, 16);
        p += __shfl_xor(p, 32);
        if (g == 0) xhp[buf][j][w] = p;

        const unsigned pH0 = cvt_pk_bf16(h[0], h[1]);
        const unsigned pH1 = cvt_pk_bf16(h[2], h[3]);
        const float l0 = h[0] - __uint_as_float(pH0 << 16);
        const float l1 = h[1] - __uint_as_float(pH0 & 0xFFFF0000u);
        const float l2 = h[2] - __uint_as_float(pH1 << 16);
        const float l3 = h[3] - __uint_as_float(pH1 & 0xFFFF0000u);
        const unsigned pL0 = cvt_pk_bf16(l0, l1);
        const unsigned pL1 = cvt_pk_bf16(l2, l3);
        {
            const int off = j * HROW + u0;        // ushort index, 8B-aligned
            uint2 vH; vH.x = pH0; vH.y = pH1;
            uint2 vL; vL.x = pL0; vL.y = pL1;
            *(uint2*)&h_lds[buf][0][off] = vH;
            *(uint2*)&h_lds[buf][1][off] = vL;
        }
        __syncthreads();

        // ---- phase B: h B-frags (4x ds_read_b128) + xh gather + 18 MFMA ----
        Frag A[2][2];
#pragma unroll
        for (int kt = 0; kt < 2; ++kt)
#pragma unroll
            for (int lev = 0; lev < 2; ++lev)
                A[kt][lev].v = *(const short8v*)&h_lds[buf][lev][j * HROW + kt * 32 + 8 * g];
        const float4 px = *(const float4*)&xhp[buf][j][0];     // broadcast read

        f32x4 acc0 = {0,0,0,0}, acc1 = {0,0,0,0}, acc2 = {0,0,0,0};
#pragma unroll
        for (int kt = 0; kt < 2; ++kt) {
            // products (W_lev, h_lev): {(0,0),(0,1),(1,0)}; acc rotation r,n,z
            acc0 = __builtin_amdgcn_mfma_f32_16x16x32_bf16(Wf[0][kt][0].v, A[kt][0].v, acc0, 0, 0, 0);
            acc2 = __builtin_amdgcn_mfma_f32_16x16x32_bf16(Wf[2][kt][0].v, A[kt][0].v, acc2, 0, 0, 0);
            acc1 = __builtin_amdgcn_mfma_f32_16x16x32_bf16(Wf[1][kt][0].v, A[kt][0].v, acc1, 0, 0, 0);
            acc0 = __builtin_amdgcn_mfma_f32_16x16x32_bf16(Wf[0][kt][0].v, A[kt][1].v, acc0, 0, 0, 0);
            acc2 = __builtin_amdgcn_mfma_f32_16x16x32_bf16(Wf[2][kt][0].v, A[kt][1].v, acc2, 0, 0, 0);
            acc1 = __builtin_amdgcn_mfma_f32_16x16x32_bf16(Wf[1][kt][0].v, A[kt][1].v, acc1, 0, 0, 0);
            acc0 = __builtin_amdgcn_mfma_f32_16x16x32_bf16(Wf[0][kt][1].v, A[kt][0].v, acc0, 0, 0, 0);
            acc2 = __builtin_amdgcn_mfma_f32_16x16x32_bf16(Wf[2][kt][1].v, A[kt][0].v, acc2, 0, 0, 0);
            acc1 = __builtin_amdgcn_mfma_f32_16x16x32_bf16(Wf[1][kt][1].v, A[kt][0].v, acc1, 0, 0, 0);
        }

        // ---- phase C: per-seq scalars once, then 4 units of gates ----
        const float xh = px.x + px.y + px.z + px.w + rb0;
        if (w == 0 && g == 0) impbuf[j][tm] = xh;
        const float mv = xmd.y;
        const float xc = mv * xmd.x + (1.0f - mv) * xh;
#pragma unroll
        for (int q = 0; q < 4; ++q) {
            const float an = wxn[q] * xc + wmn[q] * mv + binq[q];   // indep of rr (2*L2E space)
            const float bn = acc2[q] + bhnq[q];                     // indep of rr (2*L2E space)
            const float rr = fsig2(acc0[q] + wxr[q] * xc + wmr[q] * mv + brq[q]);
            const float zz = fsig2(acc1[q] + wxz[q] * xc + wmz[q] * mv + bzq[q]);
            const float nn = 2.0f * __builtin_amdgcn_rcpf(1.0f + exp2f(-(an + rr * bn))) - 1.0f;
            h[q] = nn + zz * (h[q] - nn);
        }
    }

    // epilogue: flush last imp chunk + fc reduction
    __syncthreads();
    {
        const int fs = tid >> 4, ft = tid & 15;
        impOut[fs * NT + (NT - 16) + ft] = impbuf[fs][ft];
    }
    float pfc = h[0] * fcq[0] + h[1] * fcq[1] + h[2] * fcq[2] + h[3] * fcq[3];
    pfc += __shfl_xor(pfc, 16);
    pfc += __shfl_xor(pfc, 32);
    if (lane < 16) fcpart[j][w] = pfc;
    __syncthreads();
    if (tid < 16) {
        float4 xp = *(const float4*)&fcpart[tid][0];
        ws[dir * 2048 + b0 + tid] = xp.x + xp.y + xp.z + xp.w + fcb[0];
    }
}

__global__ void brits_combine(const float* __restrict__ ws, float* __restrict__ out)
{
    int i = blockIdx.x * 256 + threadIdx.x;
    if (i < 2048) out[i] = 0.5f * (ws[i] + ws[2048 + i]);
}

extern "C" void kernel_launch(void* const* d_in, const int* in_sizes, int n_in,
                              void* d_out, int out_size, void* d_ws, size_t ws_size,
                              hipStream_t stream)
{
    const float* p[21];
    for (int i = 0; i < 21; ++i) p[i] = (const float*)d_in[i];
    float* out = (float*)d_out;
    float* ws  = (float*)d_ws;   // 4096 floats used

    brits_mfma<<<256, 256, 0, stream>>>(
        p[0],
        p[1], p[2], p[3], p[4], p[5], p[6], p[7], p[8], p[9], p[10],
        p[11], p[12], p[13], p[14], p[15], p[16], p[17], p[18], p[19], p[20],
        out, ws);
    brits_combine<<<8, 256, 0, stream>>>(ws, out);
}

// Round 10
// 394.226 us; speedup vs baseline: 1.4640x; 1.1942x over previous
//
#include <hip/hip_runtime.h>

#define NT   512
#define IMPN (2048 * 512)
#define HROW 72                      // ushorts per h_lds seq-row (144 B, 16B-aligned)

typedef __attribute__((ext_vector_type(8))) short short8v;
typedef __attribute__((ext_vector_type(4))) float f32x4;

union Frag { short8v v; unsigned short s[8]; };

#define L2E 1.4426950408889634f

// sigmoid in exp2-prescaled space: arg y2 = y_natural * log2(e)
__device__ __forceinline__ float fsig2(float y2) {
    return __builtin_amdgcn_rcpf(1.0f + exp2f(-y2));
}
__device__ __forceinline__ unsigned short f2bf(float f) {
    unsigned u = __float_as_uint(f);
    unsigned r = u + 0x7FFFu + ((u >> 16) & 1u);
    return (unsigned short)(r >> 16);
}
__device__ __forceinline__ float bf2f(unsigned short s) {
    return __uint_as_float(((unsigned)s) << 16);
}
__device__ __forceinline__ unsigned cvt_pk_bf16(float a, float b) {
    unsigned r;
    asm("v_cvt_pk_bf16_f32 %0, %1, %2" : "=v"(r) : "v"(a), "v"(b));
    return r;
}

// 256 blocks x 256 threads, 1 block/CU (1024 full-lane waves = 1 wave/SIMD
// chip-wide; R6/R8 proved 2-stream variants waste lanes or idle CUs; R9 proved
// serial cross-lane latency costs more than MFMA issue slots). Blocks 0..127
// fwd, 128..255 bwd; block = 16 seqs. TRANSPOSED MFMA (weights = A, h = B):
// D[gate-row][seq], lane (j,g) owns seq j, units 16w+4g+{0..3}.
// 18 MFMA/step: {W_H*h_H, W_H*h_L} for r,z,n (W single-level bf16: static
// quantization ~2^-9 -> final err ~<=1e-3, under the bf16 output floor) and
// {rW_H*h_H, rW_H*h_L, rW_L*h_H} for xh=acc3 (imp output path kept 3-product).
// exp2 PRESCALING: r/z paths scaled by log2e, n path by 2*log2e, decay by
// log2e; rW/acc3 stays NATURAL scale (xh/imp/xc exact).
// xmd (x,m,d) consumed from registers; next step's float4 prefetched during
// phase B so its LDS latency hides under MFMA+gates.
// dir=1 consumes time REVERSED; imp stored at scan index.
__global__ __launch_bounds__(256, 1) void brits_mfma(
    const float* __restrict__ input,
    const float* __restrict__ gW_f, const float* __restrict__ gb_f,
    const float* __restrict__ rW_f, const float* __restrict__ rb_f,
    const float* __restrict__ fcW_f, const float* __restrict__ fcb_f,
    const float* __restrict__ Wih_f, const float* __restrict__ bih_f,
    const float* __restrict__ Whh_f, const float* __restrict__ bhh_f,
    const float* __restrict__ gW_b, const float* __restrict__ gb_b,
    const float* __restrict__ rW_b, const float* __restrict__ rb_b,
    const float* __restrict__ fcW_b, const float* __restrict__ fcb_b,
    const float* __restrict__ Wih_b, const float* __restrict__ bih_b,
    const float* __restrict__ Whh_b, const float* __restrict__ bhh_b,
    float* __restrict__ out, float* __restrict__ ws)
{
    __shared__ __align__(16) unsigned short h_lds[2][2][16 * HROW]; // [buf][lev][seq*HROW+unit]
    __shared__ __align__(16) float xmd_l[16][17][4];                // [seq][tau(+pad)][x,m,d,-]
    __shared__ __align__(16) float impbuf[16][17];
    __shared__ __align__(16) float fcpart[16][4];

    const int tid  = threadIdx.x;
    const int w    = tid >> 6;
    const int lane = tid & 63;
    const int j    = lane & 15;          // seq owned by this lane
    const int g    = lane >> 4;
    const int u    = w * 16 + j;         // weight-frag row unit
    const int u0   = w * 16 + 4 * g;     // first of this lane's 4 gate units
    const int dir  = blockIdx.x >> 7;
    const int b0   = (blockIdx.x & 127) * 16;

    const float* gW  = dir ? gW_b  : gW_f;
    const float* gb  = dir ? gb_b  : gb_f;
    const float* rW  = dir ? rW_b  : rW_f;
    const float* rb  = dir ? rb_b  : rb_f;
    const float* fcW = dir ? fcW_b : fcW_f;
    const float* fcb = dir ? fcb_b : fcb_f;
    const float* Wih = dir ? Wih_b : Wih_f;
    const float* bih = dir ? bih_b : bih_f;
    const float* Whh = dir ? Whh_b : Whh_f;
    const float* bhh = dir ? bhh_b : bhh_f;

    // per-lane per-q constants (units u0..u0+3), exp2-prescaled
    float gW2[4], gb2[4], fcq[4];
    float wxr[4], wmr[4], wxz[4], wmz[4], wxn[4], wmn[4];
    float brq[4], bzq[4], binq[4], bhnq[4];
#pragma unroll
    for (int q = 0; q < 4; ++q) {
        const int uq = u0 + q;
        gW2[q] = gW[uq] * L2E; gb2[q] = gb[uq] * L2E;
        fcq[q] = fcW[uq];
        wxr[q] = Wih[2 * uq] * L2E;                wmr[q] = Wih[2 * uq + 1] * L2E;
        wxz[q] = Wih[2 * (64 + uq)] * L2E;         wmz[q] = Wih[2 * (64 + uq) + 1] * L2E;
        wxn[q] = Wih[2 * (128 + uq)] * 2.0f * L2E; wmn[q] = Wih[2 * (128 + uq) + 1] * 2.0f * L2E;
        brq[q]  = (bih[uq] + bhh[uq]) * L2E;
        bzq[q]  = (bih[64 + uq] + bhh[64 + uq]) * L2E;
        binq[q] = bih[128 + uq] * 2.0f * L2E;
        bhnq[q] = bhh[128 + uq] * 2.0f * L2E;
    }
    const float rb0 = rb[0];

    // weight A-fragments: WfH = bf16(H) of prescaled Whh r/z/n rows + natural
    // rW; rWL = bf16 residual of rW only (3-product xh path).
    Frag WfH[4][2]; Frag rWL[2];
#pragma unroll
    for (int t = 0; t < 4; ++t) {
        const float* src = (t < 3) ? (Whh + (t * 64 + u) * 64) : rW;
        const float sc = (t == 2) ? (2.0f * L2E) : ((t == 3) ? 1.0f : L2E);
#pragma unroll
        for (int kt = 0; kt < 2; ++kt) {
#pragma unroll
            for (int e = 0; e < 8; ++e) {
                const float v = src[kt * 32 + g * 8 + e] * sc;
                const unsigned short bH = f2bf(v);
                WfH[t][kt].s[e] = bH;
                if (t == 3) rWL[kt].s[e] = f2bf(v - bf2f(bH));  // RNE residual
            }
        }
    }

    const float* inp = input + (size_t)b0 * 3072;
    float* impOut = out + 2048 + (size_t)dir * IMPN + (size_t)b0 * NT;

    float h[4] = {0.0f, 0.0f, 0.0f, 0.0f};   // units u0..u0+3, seq j
    float4 xmd;                               // current step x,m,d (register)

    for (int t = 0; t < NT; ++t) {
        const int tm = t & 15;
        if (tm == 0) {                            // 16-step chunk boundary
            __syncthreads();
            const int s = tid >> 4, tmi = tid & 15;
            if (t > 0) {                          // coalesced imp flush
                impOut[s * NT + (t - 16) + tmi] = impbuf[s][tmi];
            }
            {                                     // stage x/m/d chunk (scan order)
                const float* base = inp + (size_t)s * 3072;
                const int tt = dir ? (NT - 1 - t - tmi) : (t + tmi);
                float x = base[tt];
                x = (x != x) ? -1.0f : x;
                const float m  = base[2 * NT + tt];
                const float dd = base[3 * NT + tt];
                float4 v; v.x = x; v.y = m; v.z = dd; v.w = 0.0f;
                *(float4*)&xmd_l[s][tmi][0] = v;
            }
            __syncthreads();
            xmd = *(const float4*)&xmd_l[j][0][0];
        }
        const int buf = t & 1;

        // ---- phase A: decay (regs only), pack H/L, publish (2x b64) ----
#pragma unroll
        for (int q = 0; q < 4; ++q) h[q] *= fsig2(xmd.z * gW2[q] + gb2[q]);

        const unsigned pH0 = cvt_pk_bf16(h[0], h[1]);
        const unsigned pH1 = cvt_pk_bf16(h[2], h[3]);
        const float l0 = h[0] - __uint_as_float(pH0 << 16);
        const float l1 = h[1] - __uint_as_float(pH0 & 0xFFFF0000u);
        const float l2 = h[2] - __uint_as_float(pH1 << 16);
        const float l3 = h[3] - __uint_as_float(pH1 & 0xFFFF0000u);
        const unsigned pL0 = cvt_pk_bf16(l0, l1);
        const unsigned pL1 = cvt_pk_bf16(l2, l3);
        {
            const int off = j * HROW + u0;        // ushort index, 8B-aligned
            uint2 vH; vH.x = pH0; vH.y = pH1;
            uint2 vL; vL.x = pL0; vL.y = pL1;
            *(uint2*)&h_lds[buf][0][off] = vH;
            *(uint2*)&h_lds[buf][1][off] = vL;
        }
        __syncthreads();

        // ---- phase B: h B-frags (4x ds_read_b128) + xmd prefetch + 18 MFMA ----
        Frag A[2][2];
#pragma unroll
        for (int kt = 0; kt < 2; ++kt)
#pragma unroll
            for (int lev = 0; lev < 2; ++lev)
                A[kt][lev].v = *(const short8v*)&h_lds[buf][lev][j * HROW + kt * 32 + 8 * g];
        const float4 xmd_nxt = *(const float4*)&xmd_l[j][(tm + 1) & 15][0];

        f32x4 acc0 = {0,0,0,0}, acc1 = {0,0,0,0}, acc2 = {0,0,0,0}, acc3 = {0,0,0,0};
#pragma unroll
        for (int kt = 0; kt < 2; ++kt) {
            acc3 = __builtin_amdgcn_mfma_f32_16x16x32_bf16(WfH[3][kt].v, A[kt][0].v, acc3, 0, 0, 0);
            acc0 = __builtin_amdgcn_mfma_f32_16x16x32_bf16(WfH[0][kt].v, A[kt][0].v, acc0, 0, 0, 0);
            acc2 = __builtin_amdgcn_mfma_f32_16x16x32_bf16(WfH[2][kt].v, A[kt][0].v, acc2, 0, 0, 0);
            acc1 = __builtin_amdgcn_mfma_f32_16x16x32_bf16(WfH[1][kt].v, A[kt][0].v, acc1, 0, 0, 0);
            acc3 = __builtin_amdgcn_mfma_f32_16x16x32_bf16(WfH[3][kt].v, A[kt][1].v, acc3, 0, 0, 0);
            acc0 = __builtin_amdgcn_mfma_f32_16x16x32_bf16(WfH[0][kt].v, A[kt][1].v, acc0, 0, 0, 0);
            acc2 = __builtin_amdgcn_mfma_f32_16x16x32_bf16(WfH[2][kt].v, A[kt][1].v, acc2, 0, 0, 0);
            acc1 = __builtin_amdgcn_mfma_f32_16x16x32_bf16(WfH[1][kt].v, A[kt][1].v, acc1, 0, 0, 0);
            acc3 = __builtin_amdgcn_mfma_f32_16x16x32_bf16(rWL[kt].v,   A[kt][0].v, acc3, 0, 0, 0);
        }

        // ---- phase C: per-seq scalars once, then 4 units of gates ----
        const float xh = acc3[0] + rb0;           // all acc3 rows identical (bcast A)
        if (w == 0 && g == 0) impbuf[j][tm] = xh;
        const float mv = xmd.y;
        const float xc = mv * xmd.x + (1.0f - mv) * xh;
#pragma unroll
        for (int q = 0; q < 4; ++q) {
            const float an = wxn[q] * xc + wmn[q] * mv + binq[q];   // indep of rr (2*L2E space)
            const float bn = acc2[q] + bhnq[q];                     // indep of rr (2*L2E space)
            const float rr = fsig2(acc0[q] + wxr[q] * xc + wmr[q] * mv + brq[q]);
            const float zz = fsig2(acc1[q] + wxz[q] * xc + wmz[q] * mv + bzq[q]);
            const float nn = 2.0f * __builtin_amdgcn_rcpf(1.0f + exp2f(-(an + rr * bn))) - 1.0f;
            h[q] = nn + zz * (h[q] - nn);
        }
        xmd = xmd_nxt;
    }

    // epilogue: flush last imp chunk + fc reduction
    __syncthreads();
    {
        const int fs = tid >> 4, ft = tid & 15;
        impOut[fs * NT + (NT - 16) + ft] = impbuf[fs][ft];
    }
    float pfc = h[0] * fcq[0] + h[1] * fcq[1] + h[2] * fcq[2] + h[3] * fcq[3];
    pfc += __shfl_xor(pfc, 16);
    pfc += __shfl_xor(pfc, 32);
    if (lane < 16) fcpart[j][w] = pfc;
    __syncthreads();
    if (tid < 16) {
        float4 xp = *(const float4*)&fcpart[tid][0];
        ws[dir * 2048 + b0 + tid] = xp.x + xp.y + xp.z + xp.w + fcb[0];
    }
}

__global__ void brits_combine(const float* __restrict__ ws, float* __restrict__ out)
{
    int i = blockIdx.x * 256 + threadIdx.x;
    if (i < 2048) out[i] = 0.5f * (ws[i] + ws[2048 + i]);
}

extern "C" void kernel_launch(void* const* d_in, const int* in_sizes, int n_in,
                              void* d_out, int out_size, void* d_ws, size_t ws_size,
                              hipStream_t stream)
{
    const float* p[21];
    for (int i = 0; i < 21; ++i) p[i] = (const float*)d_in[i];
    float* out = (float*)d_out;
    float* ws  = (float*)d_ws;   // 4096 floats used

    brits_mfma<<<256, 256, 0, stream>>>(
        p[0],
        p[1], p[2], p[3], p[4], p[5], p[6], p[7], p[8], p[9], p[10],
        p[11], p[12], p[13], p[14], p[15], p[16], p[17], p[18], p[19], p[20],
        out, ws);
    brits_combine<<<8, 256, 0, stream>>>(ws, out);
}

// Round 11
// 313.298 us; speedup vs baseline: 1.8422x; 1.2583x over previous
//
#include <hip/hip_runtime.h>

#define NT   512
#define IMPN (2048 * 512)
#define HROW 72                      // ushorts per h_lds seq-row (144 B, 16B-aligned)

typedef __attribute__((ext_vector_type(8))) short short8v;
typedef __attribute__((ext_vector_type(4))) float f32x4;

union Frag { short8v v; unsigned short s[8]; };

#define L2E 1.4426950408889634f

// bare v_exp_f32 (2^x): 1 instruction, ~1ulp, inf/0 saturation correct.
// exp2f() libm is NOT used: it costs ~10+ VALU inst in edge handling (R10).
__device__ __forceinline__ float fexp2(float x) {
    float r;
    asm("v_exp_f32 %0, %1" : "=v"(r) : "v"(x));
    return r;
}
__device__ __forceinline__ unsigned short f2bf(float f) {
    unsigned u = __float_as_uint(f);
    unsigned r = u + 0x7FFFu + ((u >> 16) & 1u);
    return (unsigned short)(r >> 16);
}
__device__ __forceinline__ float bf2f(unsigned short s) {
    return __uint_as_float(((unsigned)s) << 16);
}
__device__ __forceinline__ unsigned cvt_pk_bf16(float a, float b) {
    unsigned r;
    asm("v_cvt_pk_bf16_f32 %0, %1, %2" : "=v"(r) : "v"(a), "v"(b));
    return r;
}

// 256 blocks x 256 threads, 1 block/CU (1024 full-lane waves = 1 wave/SIMD
// chip-wide; R6/R8: 2-stream variants waste lanes or idle CUs; R9: serial
// cross-lane latency costs more than MFMA issue slots; R10: libm exp2f costs
// ~400 cyc/step of VALU). Blocks 0..127 fwd, 128..255 bwd; block = 16 seqs.
// TRANSPOSED MFMA (weights = A, h = B): D[gate-row][seq], lane (j,g) owns
// seq j, units 16w+4g+{0..3}.
// 18 MFMA/step: {W_H*h_H, W_H*h_L} for r,z,n (W single-level bf16; static
// quant ~2^-9 -> final err <=1e-3, under bf16 output floor) + 3-product rW
// path for xh=acc3 (imp output, natural scale, fp32-grade).
// NEGATED exp2 PRESCALING: r/z paths x(-log2e), n path x(-2log2e), decay
// x(-log2e) -> MFMA/FMA chains produce the exp2 argument directly;
// sig = rcp(1+exp2(arg)), tanh = 2*rcp(1+exp2(arg2))-1; zero muls/negs in the
// transcendental chains. xmd consumed from registers (prefetched in phase B).
// dir=1 consumes time REVERSED; imp stored at scan index.
__global__ __launch_bounds__(256, 1) void brits_mfma(
    const float* __restrict__ input,
    const float* __restrict__ gW_f, const float* __restrict__ gb_f,
    const float* __restrict__ rW_f, const float* __restrict__ rb_f,
    const float* __restrict__ fcW_f, const float* __restrict__ fcb_f,
    const float* __restrict__ Wih_f, const float* __restrict__ bih_f,
    const float* __restrict__ Whh_f, const float* __restrict__ bhh_f,
    const float* __restrict__ gW_b, const float* __restrict__ gb_b,
    const float* __restrict__ rW_b, const float* __restrict__ rb_b,
    const float* __restrict__ fcW_b, const float* __restrict__ fcb_b,
    const float* __restrict__ Wih_b, const float* __restrict__ bih_b,
    const float* __restrict__ Whh_b, const float* __restrict__ bhh_b,
    float* __restrict__ out, float* __restrict__ ws)
{
    __shared__ __align__(16) unsigned short h_lds[2][2][16 * HROW]; // [buf][lev][seq*HROW+unit]
    __shared__ __align__(16) float xmd_l[16][17][4];                // [seq][tau(+pad)][x,m,d,-]
    __shared__ __align__(16) float impbuf[16][17];
    __shared__ __align__(16) float fcpart[16][4];

    const int tid  = threadIdx.x;
    const int w    = tid >> 6;
    const int lane = tid & 63;
    const int j    = lane & 15;          // seq owned by this lane
    const int g    = lane >> 4;
    const int u    = w * 16 + j;         // weight-frag row unit
    const int u0   = w * 16 + 4 * g;     // first of this lane's 4 gate units
    const int dir  = blockIdx.x >> 7;
    const int b0   = (blockIdx.x & 127) * 16;

    const float* gW  = dir ? gW_b  : gW_f;
    const float* gb  = dir ? gb_b  : gb_f;
    const float* rW  = dir ? rW_b  : rW_f;
    const float* rb  = dir ? rb_b  : rb_f;
    const float* fcW = dir ? fcW_b : fcW_f;
    const float* fcb = dir ? fcb_b : fcb_f;
    const float* Wih = dir ? Wih_b : Wih_f;
    const float* bih = dir ? bih_b : bih_f;
    const float* Whh = dir ? Whh_b : Whh_f;
    const float* bhh = dir ? bhh_b : bhh_f;

    // per-lane per-q constants (units u0..u0+3), NEGATED exp2-prescaled
    float gW2[4], gb2[4], fcq[4];
    float wxr[4], wmr[4], wxz[4], wmz[4], wxn[4], wmn[4];
    float brq[4], bzq[4], binq[4], bhnq[4];
#pragma unroll
    for (int q = 0; q < 4; ++q) {
        const int uq = u0 + q;
        gW2[q] = gW[uq] * -L2E; gb2[q] = gb[uq] * -L2E;
        fcq[q] = fcW[uq];
        wxr[q] = Wih[2 * uq] * -L2E;                wmr[q] = Wih[2 * uq + 1] * -L2E;
        wxz[q] = Wih[2 * (64 + uq)] * -L2E;         wmz[q] = Wih[2 * (64 + uq) + 1] * -L2E;
        wxn[q] = Wih[2 * (128 + uq)] * -2.0f * L2E; wmn[q] = Wih[2 * (128 + uq) + 1] * -2.0f * L2E;
        brq[q]  = (bih[uq] + bhh[uq]) * -L2E;
        bzq[q]  = (bih[64 + uq] + bhh[64 + uq]) * -L2E;
        binq[q] = bih[128 + uq] * -2.0f * L2E;
        bhnq[q] = bhh[128 + uq] * -2.0f * L2E;
    }
    const float rb0 = rb[0];

    // weight A-fragments: WfH = bf16(H) of NEG-prescaled Whh r/z/n rows +
    // natural rW; rWL = bf16 residual of rW only (3-product xh path).
    Frag WfH[4][2]; Frag rWL[2];
#pragma unroll
    for (int t = 0; t < 4; ++t) {
        const float* src = (t < 3) ? (Whh + (t * 64 + u) * 64) : rW;
        const float sc = (t == 2) ? (-2.0f * L2E) : ((t == 3) ? 1.0f : -L2E);
#pragma unroll
        for (int kt = 0; kt < 2; ++kt) {
#pragma unroll
            for (int e = 0; e < 8; ++e) {
                const float v = src[kt * 32 + g * 8 + e] * sc;
                const unsigned short bH = f2bf(v);
                WfH[t][kt].s[e] = bH;
                if (t == 3) rWL[kt].s[e] = f2bf(v - bf2f(bH));  // RNE residual
            }
        }
    }

    const float* inp = input + (size_t)b0 * 3072;
    float* impOut = out + 2048 + (size_t)dir * IMPN + (size_t)b0 * NT;

    float h[4] = {0.0f, 0.0f, 0.0f, 0.0f};   // units u0..u0+3, seq j
    float4 xmd;                               // current step x,m,d (register)

    for (int t = 0; t < NT; ++t) {
        const int tm = t & 15;
        if (tm == 0) {                            // 16-step chunk boundary
            __syncthreads();
            const int s = tid >> 4, tmi = tid & 15;
            if (t > 0) {                          // coalesced imp flush
                impOut[s * NT + (t - 16) + tmi] = impbuf[s][tmi];
            }
            {                                     // stage x/m/d chunk (scan order)
                const float* base = inp + (size_t)s * 3072;
                const int tt = dir ? (NT - 1 - t - tmi) : (t + tmi);
                float x = base[tt];
                x = (x != x) ? -1.0f : x;
                const float m  = base[2 * NT + tt];
                const float dd = base[3 * NT + tt];
                float4 v; v.x = x; v.y = m; v.z = dd; v.w = 0.0f;
                *(float4*)&xmd_l[s][tmi][0] = v;
            }
            __syncthreads();
            xmd = *(const float4*)&xmd_l[j][0][0];
        }
        const int buf = t & 1;

        // ---- phase A: decay (arg = neg-prescaled), pack H/L, publish ----
#pragma unroll
        for (int q = 0; q < 4; ++q)
            h[q] *= __builtin_amdgcn_rcpf(1.0f + fexp2(xmd.z * gW2[q] + gb2[q]));

        const unsigned pH0 = cvt_pk_bf16(h[0], h[1]);
        const unsigned pH1 = cvt_pk_bf16(h[2], h[3]);
        const float l0 = h[0] - __uint_as_float(pH0 << 16);
        const float l1 = h[1] - __uint_as_float(pH0 & 0xFFFF0000u);
        const float l2 = h[2] - __uint_as_float(pH1 << 16);
        const float l3 = h[3] - __uint_as_float(pH1 & 0xFFFF0000u);
        const unsigned pL0 = cvt_pk_bf16(l0, l1);
        const unsigned pL1 = cvt_pk_bf16(l2, l3);
        {
            const int off = j * HROW + u0;        // ushort index, 8B-aligned
            uint2 vH; vH.x = pH0; vH.y = pH1;
            uint2 vL; vL.x = pL0; vL.y = pL1;
            *(uint2*)&h_lds[buf][0][off] = vH;
            *(uint2*)&h_lds[buf][1][off] = vL;
        }
        __syncthreads();

        // ---- phase B: h B-frags (4x ds_read_b128) + xmd prefetch + 18 MFMA ----
        Frag A[2][2];
#pragma unroll
        for (int kt = 0; kt < 2; ++kt)
#pragma unroll
            for (int lev = 0; lev < 2; ++lev)
                A[kt][lev].v = *(const short8v*)&h_lds[buf][lev][j * HROW + kt * 32 + 8 * g];
        const float4 xmd_nxt = *(const float4*)&xmd_l[j][(tm + 1) & 15][0];

        f32x4 acc0 = {0,0,0,0}, acc1 = {0,0,0,0}, acc2 = {0,0,0,0}, acc3 = {0,0,0,0};
#pragma unroll
        for (int kt = 0; kt < 2; ++kt) {
            acc3 = __builtin_amdgcn_mfma_f32_16x16x32_bf16(WfH[3][kt].v, A[kt][0].v, acc3, 0, 0, 0);
            acc0 = __builtin_amdgcn_mfma_f32_16x16x32_bf16(WfH[0][kt].v, A[kt][0].v, acc0, 0, 0, 0);
            acc2 = __builtin_amdgcn_mfma_f32_16x16x32_bf16(WfH[2][kt].v, A[kt][0].v, acc2, 0, 0, 0);
            acc1 = __builtin_amdgcn_mfma_f32_16x16x32_bf16(WfH[1][kt].v, A[kt][0].v, acc1, 0, 0, 0);
            acc3 = __builtin_amdgcn_mfma_f32_16x16x32_bf16(WfH[3][kt].v, A[kt][1].v, acc3, 0, 0, 0);
            acc0 = __builtin_amdgcn_mfma_f32_16x16x32_bf16(WfH[0][kt].v, A[kt][1].v, acc0, 0, 0, 0);
            acc2 = __builtin_amdgcn_mfma_f32_16x16x32_bf16(WfH[2][kt].v, A[kt][1].v, acc2, 0, 0, 0);
            acc1 = __builtin_amdgcn_mfma_f32_16x16x32_bf16(WfH[1][kt].v, A[kt][1].v, acc1, 0, 0, 0);
            acc3 = __builtin_amdgcn_mfma_f32_16x16x32_bf16(rWL[kt].v,   A[kt][0].v, acc3, 0, 0, 0);
        }

        // ---- phase C: per-seq scalars once, then 4 units of gates ----
        const float xh = acc3[0] + rb0;           // all acc3 rows identical (bcast A)
        if (w == 0 && g == 0) impbuf[j][tm] = xh;
        const float mv = xmd.y;
        const float xc = mv * xmd.x + (1.0f - mv) * xh;
#pragma unroll
        for (int q = 0; q < 4; ++q) {
            // all args already negated+scaled: exp2(arg) directly
            const float an = wxn[q] * xc + wmn[q] * mv + binq[q];   // -2L2E space
            const float bn = acc2[q] + bhnq[q];                     // -2L2E space
            const float rr = __builtin_amdgcn_rcpf(1.0f + fexp2(acc0[q] + wxr[q] * xc + wmr[q] * mv + brq[q]));
            const float zz = __builtin_amdgcn_rcpf(1.0f + fexp2(acc1[q] + wxz[q] * xc + wmz[q] * mv + bzq[q]));
            const float nn = 2.0f * __builtin_amdgcn_rcpf(1.0f + fexp2(an + rr * bn)) - 1.0f;
            h[q] = nn + zz * (h[q] - nn);
        }
        xmd = xmd_nxt;
    }

    // epilogue: flush last imp chunk + fc reduction
    __syncthreads();
    {
        const int fs = tid >> 4, ft = tid & 15;
        impOut[fs * NT + (NT - 16) + ft] = impbuf[fs][ft];
    }
    float pfc = h[0] * fcq[0] + h[1] * fcq[1] + h[2] * fcq[2] + h[3] * fcq[3];
    pfc += __shfl_xor(pfc, 16);
    pfc += __shfl_xor(pfc, 32);
    if (lane < 16) fcpart[j][w] = pfc;
    __syncthreads();
    if (tid < 16) {
        float4 xp = *(const float4*)&fcpart[tid][0];
        ws[dir * 2048 + b0 + tid] = xp.x + xp.y + xp.z + xp.w + fcb[0];
    }
}

__global__ void brits_combine(const float* __restrict__ ws, float* __restrict__ out)
{
    int i = blockIdx.x * 256 + threadIdx.x;
    if (i < 2048) out[i] = 0.5f * (ws[i] + ws[2048 + i]);
}

extern "C" void kernel_launch(void* const* d_in, const int* in_sizes, int n_in,
                              void* d_out, int out_size, void* d_ws, size_t ws_size,
                              hipStream_t stream)
{
    const float* p[21];
    for (int i = 0; i < 21; ++i) p[i] = (const float*)d_in[i];
    float* out = (float*)d_out;
    float* ws  = (float*)d_ws;   // 4096 floats used

    brits_mfma<<<256, 256, 0, stream>>>(
        p[0],
        p[1], p[2], p[3], p[4], p[5], p[6], p[7], p[8], p[9], p[10],
        p[11], p[12], p[13], p[14], p[15], p[16], p[17], p[18], p[19], p[20],
        out, ws);
    brits_combine<<<8, 256, 0, stream>>>(ws, out);
}

// Round 12
// 261.043 us; speedup vs baseline: 2.2109x; 1.2002x over previous
//
#include <hip/hip_runtime.h>

#define NT   512
#define IMPN (2048 * 512)
#define HROW 72                      // ushorts per h_lds seq-row (144 B, 16B-aligned)

typedef __attribute__((ext_vector_type(8))) short short8v;
typedef __attribute__((ext_vector_type(4))) float f32x4;

union Frag { short8v v; unsigned short s[8]; };

#define L2E 1.4426950408889634f

// bare v_exp_f32 (2^x): 1 instruction (libm exp2f costs ~10+ VALU, R10).
__device__ __forceinline__ float fexp2(float x) {
    float r;
    asm("v_exp_f32 %0, %1" : "=v"(r) : "v"(x));
    return r;
}
__device__ __forceinline__ unsigned short f2bf(float f) {
    unsigned u = __float_as_uint(f);
    unsigned r = u + 0x7FFFu + ((u >> 16) & 1u);
    return (unsigned short)(r >> 16);
}
__device__ __forceinline__ float bf2f(unsigned short s) {
    return __uint_as_float(((unsigned)s) << 16);
}
__device__ __forceinline__ unsigned cvt_pk_bf16(float a, float b) {
    unsigned r;
    asm("v_cvt_pk_bf16_f32 %0, %1, %2" : "=v"(r) : "v"(a), "v"(b));
    return r;
}

// 256 blocks x 256 threads, 1 block/CU (1024 full-lane waves = 1 wave/SIMD
// chip-wide; R6/R8: multi-stream variants waste lanes or idle CUs; R9: serial
// cross-lane latency > MFMA issue cost; R10/R11: bare v_exp_f32 only).
// Blocks 0..127 fwd, 128..255 bwd; block = 16 seqs. TRANSPOSED MFMA
// (weights = A, h = B): D[gate-row][seq], lane (j,g) owns seq j, units
// 16w+4g+{0..3}.
// 10 MFMA/step (was 18): SINGLE-LEVEL h (bf16 RNE, no h_L plane): r,z,n =
// W_H*h_H (2 kt each = 6); xh = {rW_H*h_H, rW_L*h_H} (2 kt each = 4, W-side
// 2-level kept for imp precision). Precision model: gate pre-act RMS err
// ~||W||2 * 2^-9 * rms(h) ~3-5e-4 -> contractive GRU -> final ~2-4e-3 < 7.5e-3
// threshold. Fallback if falsified: R11 (2-level h, 18 MFMA, 350us).
// NEGATED exp2 PRESCALING: r/z x(-log2e), n x(-2log2e), decay x(-log2e);
// rW/acc3 natural. xmd from registers (prefetched); 32-step staging chunks.
// dir=1 consumes time REVERSED; imp stored at scan index.
__global__ __launch_bounds__(256, 1) void brits_mfma(
    const float* __restrict__ input,
    const float* __restrict__ gW_f, const float* __restrict__ gb_f,
    const float* __restrict__ rW_f, const float* __restrict__ rb_f,
    const float* __restrict__ fcW_f, const float* __restrict__ fcb_f,
    const float* __restrict__ Wih_f, const float* __restrict__ bih_f,
    const float* __restrict__ Whh_f, const float* __restrict__ bhh_f,
    const float* __restrict__ gW_b, const float* __restrict__ gb_b,
    const float* __restrict__ rW_b, const float* __restrict__ rb_b,
    const float* __restrict__ fcW_b, const float* __restrict__ fcb_b,
    const float* __restrict__ Wih_b, const float* __restrict__ bih_b,
    const float* __restrict__ Whh_b, const float* __restrict__ bhh_b,
    float* __restrict__ out, float* __restrict__ ws)
{
    __shared__ __align__(16) unsigned short h_lds[2][16 * HROW]; // [buf][seq*HROW+unit]
    __shared__ __align__(16) float xmd_l[16][33][4];             // [seq][tau(+pad)][x,m,d,-]
    __shared__ __align__(16) float impbuf[16][33];
    __shared__ __align__(16) float fcpart[16][4];

    const int tid  = threadIdx.x;
    const int w    = tid >> 6;
    const int lane = tid & 63;
    const int j    = lane & 15;          // seq owned by this lane
    const int g    = lane >> 4;
    const int u    = w * 16 + j;         // weight-frag row unit
    const int u0   = w * 16 + 4 * g;     // first of this lane's 4 gate units
    const int dir  = blockIdx.x >> 7;
    const int b0   = (blockIdx.x & 127) * 16;

    const float* gW  = dir ? gW_b  : gW_f;
    const float* gb  = dir ? gb_b  : gb_f;
    const float* rW  = dir ? rW_b  : rW_f;
    const float* rb  = dir ? rb_b  : rb_f;
    const float* fcW = dir ? fcW_b : fcW_f;
    const float* fcb = dir ? fcb_b : fcb_f;
    const float* Wih = dir ? Wih_b : Wih_f;
    const float* bih = dir ? bih_b : bih_f;
    const float* Whh = dir ? Whh_b : Whh_f;
    const float* bhh = dir ? bhh_b : bhh_f;

    // per-lane per-q constants (units u0..u0+3), NEGATED exp2-prescaled
    float gW2[4], gb2[4], fcq[4];
    float wxr[4], wmr[4], wxz[4], wmz[4], wxn[4], wmn[4];
    float brq[4], bzq[4], binq[4], bhnq[4];
#pragma unroll
    for (int q = 0; q < 4; ++q) {
        const int uq = u0 + q;
        gW2[q] = gW[uq] * -L2E; gb2[q] = gb[uq] * -L2E;
        fcq[q] = fcW[uq];
        wxr[q] = Wih[2 * uq] * -L2E;                wmr[q] = Wih[2 * uq + 1] * -L2E;
        wxz[q] = Wih[2 * (64 + uq)] * -L2E;         wmz[q] = Wih[2 * (64 + uq) + 1] * -L2E;
        wxn[q] = Wih[2 * (128 + uq)] * -2.0f * L2E; wmn[q] = Wih[2 * (128 + uq) + 1] * -2.0f * L2E;
        brq[q]  = (bih[uq] + bhh[uq]) * -L2E;
        bzq[q]  = (bih[64 + uq] + bhh[64 + uq]) * -L2E;
        binq[q] = bih[128 + uq] * -2.0f * L2E;
        bhnq[q] = bhh[128 + uq] * -2.0f * L2E;
    }
    const float rb0 = rb[0];

    // weight A-fragments: WfH = bf16(H) of NEG-prescaled Whh r/z/n rows +
    // natural rW; rWL = bf16 residual of rW (xh 2nd product, imp precision).
    Frag WfH[4][2]; Frag rWL[2];
#pragma unroll
    for (int t = 0; t < 4; ++t) {
        const float* src = (t < 3) ? (Whh + (t * 64 + u) * 64) : rW;
        const float sc = (t == 2) ? (-2.0f * L2E) : ((t == 3) ? 1.0f : -L2E);
#pragma unroll
        for (int kt = 0; kt < 2; ++kt) {
#pragma unroll
            for (int e = 0; e < 8; ++e) {
                const float v = src[kt * 32 + g * 8 + e] * sc;
                const unsigned short bH = f2bf(v);
                WfH[t][kt].s[e] = bH;
                if (t == 3) rWL[kt].s[e] = f2bf(v - bf2f(bH));  // RNE residual
            }
        }
    }

    const float* inp = input + (size_t)b0 * 3072;
    float* impOut = out + 2048 + (size_t)dir * IMPN + (size_t)b0 * NT;

    float h[4] = {0.0f, 0.0f, 0.0f, 0.0f};   // units u0..u0+3, seq j
    float4 xmd;                               // current step x,m,d (register)

    for (int t = 0; t < NT; ++t) {
        const int tm = t & 31;
        if (tm == 0) {                            // 32-step chunk boundary
            __syncthreads();
            const int s = tid >> 4, tmi = tid & 15;
            if (t > 0) {                          // coalesced imp flush (2/thread)
                impOut[s * NT + (t - 32) + tmi]      = impbuf[s][tmi];
                impOut[s * NT + (t - 32) + tmi + 16] = impbuf[s][tmi + 16];
            }
            {                                     // stage x/m/d chunk (scan order)
                const float* base = inp + (size_t)s * 3072;
#pragma unroll
                for (int hh = 0; hh < 2; ++hh) {
                    const int tau = tmi + hh * 16;
                    const int tt = dir ? (NT - 1 - t - tau) : (t + tau);
                    float x = base[tt];
                    x = (x != x) ? -1.0f : x;
                    const float m  = base[2 * NT + tt];
                    const float dd = base[3 * NT + tt];
                    float4 v; v.x = x; v.y = m; v.z = dd; v.w = 0.0f;
                    *(float4*)&xmd_l[s][tau][0] = v;
                }
            }
            __syncthreads();
            xmd = *(const float4*)&xmd_l[j][0][0];
        }
        const int buf = t & 1;

        // ---- phase A: decay (neg-prescaled arg), pack H only, publish 1x b64 ----
#pragma unroll
        for (int q = 0; q < 4; ++q)
            h[q] *= __builtin_amdgcn_rcpf(1.0f + fexp2(xmd.z * gW2[q] + gb2[q]));

        const unsigned pH0 = cvt_pk_bf16(h[0], h[1]);
        const unsigned pH1 = cvt_pk_bf16(h[2], h[3]);
        {
            const int off = j * HROW + u0;        // ushort index, 8B-aligned
            uint2 vH; vH.x = pH0; vH.y = pH1;
            *(uint2*)&h_lds[buf][off] = vH;
        }
        __syncthreads();

        // ---- phase B: h B-frags (2x ds_read_b128) + xmd prefetch + 10 MFMA ----
        Frag A[2];
#pragma unroll
        for (int kt = 0; kt < 2; ++kt)
            A[kt].v = *(const short8v*)&h_lds[buf][j * HROW + kt * 32 + 8 * g];
        const float4 xmd_nxt = *(const float4*)&xmd_l[j][(tm + 1) & 31][0];

        f32x4 acc0 = {0,0,0,0}, acc1 = {0,0,0,0}, acc2 = {0,0,0,0}, acc3 = {0,0,0,0};
#pragma unroll
        for (int kt = 0; kt < 2; ++kt) {
            acc3 = __builtin_amdgcn_mfma_f32_16x16x32_bf16(WfH[3][kt].v, A[kt].v, acc3, 0, 0, 0);
            acc0 = __builtin_amdgcn_mfma_f32_16x16x32_bf16(WfH[0][kt].v, A[kt].v, acc0, 0, 0, 0);
            acc2 = __builtin_amdgcn_mfma_f32_16x16x32_bf16(WfH[2][kt].v, A[kt].v, acc2, 0, 0, 0);
            acc3 = __builtin_amdgcn_mfma_f32_16x16x32_bf16(rWL[kt].v,   A[kt].v, acc3, 0, 0, 0);
            acc1 = __builtin_amdgcn_mfma_f32_16x16x32_bf16(WfH[1][kt].v, A[kt].v, acc1, 0, 0, 0);
        }

        // ---- phase C: per-seq scalars once, then 4 units of gates ----
        const float xh = acc3[0] + rb0;           // all acc3 rows identical (bcast A)
        if (w == 0 && g == 0) impbuf[j][tm] = xh;
        const float mv = xmd.y;
        const float xc = mv * xmd.x + (1.0f - mv) * xh;
#pragma unroll
        for (int q = 0; q < 4; ++q) {
            // all args already negated+scaled: exp2(arg) directly
            const float an = wxn[q] * xc + wmn[q] * mv + binq[q];   // -2L2E space
            const float bn = acc2[q] + bhnq[q];                     // -2L2E space
            const float rr = __builtin_amdgcn_rcpf(1.0f + fexp2(acc0[q] + wxr[q] * xc + wmr[q] * mv + brq[q]));
            const float zz = __builtin_amdgcn_rcpf(1.0f + fexp2(acc1[q] + wxz[q] * xc + wmz[q] * mv + bzq[q]));
            const float nn = 2.0f * __builtin_amdgcn_rcpf(1.0f + fexp2(an + rr * bn)) - 1.0f;
            h[q] = nn + zz * (h[q] - nn);
        }
        xmd = xmd_nxt;
    }

    // epilogue: flush last imp chunk + fc reduction
    __syncthreads();
    {
        const int fs = tid >> 4, ft = tid & 15;
        impOut[fs * NT + (NT - 32) + ft]      = impbuf[fs][ft];
        impOut[fs * NT + (NT - 32) + ft + 16] = impbuf[fs][ft + 16];
    }
    float pfc = h[0] * fcq[0] + h[1] * fcq[1] + h[2] * fcq[2] + h[3] * fcq[3];
    pfc += __shfl_xor(pfc, 16);
    pfc += __shfl_xor(pfc, 32);
    if (lane < 16) fcpart[j][w] = pfc;
    __syncthreads();
    if (tid < 16) {
        float4 xp = *(const float4*)&fcpart[tid][0];
        ws[dir * 2048 + b0 + tid] = xp.x + xp.y + xp.z + xp.w + fcb[0];
    }
}

__global__ void brits_combine(const float* __restrict__ ws, float* __restrict__ out)
{
    int i = blockIdx.x * 256 + threadIdx.x;
    if (i < 2048) out[i] = 0.5f * (ws[i] + ws[2048 + i]);
}

extern "C" void kernel_launch(void* const* d_in, const int* in_sizes, int n_in,
                              void* d_out, int out_size, void* d_ws, size_t ws_size,
                              hipStream_t stream)
{
    const float* p[21];
    for (int i = 0; i < 21; ++i) p[i] = (const float*)d_in[i];
    float* out = (float*)d_out;
    float* ws  = (float*)d_ws;   // 4096 floats used

    brits_mfma<<<256, 256, 0, stream>>>(
        p[0],
        p[1], p[2], p[3], p[4], p[5], p[6], p[7], p[8], p[9], p[10],
        p[11], p[12], p[13], p[14], p[15], p[16], p[17], p[18], p[19], p[20],
        out, ws);
    brits_combine<<<8, 256, 0, stream>>>(ws, out);
}